// Round 1
// baseline (5376.191 us; speedup 1.0000x reference)
//
#include <hip/hip_runtime.h>

// GatedGCN (4 layers, N=40000, E=640000, D=128) for MI355X gfx950.
// Layout of workspace (floats):
//   h_cur[N*128] | Ah | Bh | Dh | Eh | num | den | stats[512] | etmp[E*128]
// total ~471 MB. e_cur lives in d_out's e-region (final result lands there).
// stats: [0:128) e_sum, [128:256) e_sumsq, [256:384) h_sum, [384:512) h_sumsq.

typedef __bf16 bf16x8 __attribute__((ext_vector_type(8)));
typedef float  f32x4  __attribute__((ext_vector_type(4)));

#define GCN_N 40000
#define GCN_E 640000
#define GCN_D 128

// ---------------------------------------------------------------------------
// Y[M][128] = X[M][128] @ W[128][128] + bias, bf16 MFMA, f32 in/out.
// W staged transposed in LDS as bf16 (rows padded to 136 elems = 272B to
// spread banks). Each wave: 2 m-tiles (32 rows) per iteration, grid-stride.
// Fragment mapping (verified learn_hip m91/m97):
//   A: lane l holds X[m0 + (l&15)][kc*32 + (l>>4)*8 + j], j=0..7 contiguous
//   B: lane l holds W[kc*32 + (l>>4)*8 + j][nt*16 + (l&15)]  (read from Wt)
//   D: lane l, reg r -> row = (l>>4)*4 + r, col = l&15
// ---------------------------------------------------------------------------
__global__ __launch_bounds__(256) void gemm128(const float* __restrict__ X,
                                               const float* __restrict__ W,
                                               const float* __restrict__ bias,
                                               float* __restrict__ Y, int M)
{
    __shared__ __attribute__((aligned(16))) __bf16 Wt[128 * 136];

    const int t = threadIdx.x;
    for (int i = t; i < 16384; i += 256) {
        int k = i >> 7, n = i & 127;
        Wt[n * 136 + k] = (__bf16)W[i];
    }
    __syncthreads();

    const int lane = t & 63;
    const int w    = t >> 6;
    const int l16  = lane & 15;
    const int lhi  = lane >> 4;   // 0..3

    float bv[8];
#pragma unroll
    for (int nt = 0; nt < 8; ++nt) bv[nt] = bias[nt * 16 + l16];

    const int nIter   = M >> 5;              // 32 rows / iteration (M % 32 == 0)
    const int gw      = blockIdx.x * 4 + w;
    const int gstride = gridDim.x * 4;

    for (int it = gw; it < nIter; it += gstride) {
        const int m0 = it * 32;

        bf16x8 a[2][4];
#pragma unroll
        for (int mi = 0; mi < 2; ++mi) {
            const float* xr = X + (size_t)(m0 + mi * 16 + l16) * 128 + lhi * 8;
#pragma unroll
            for (int kc = 0; kc < 4; ++kc) {
                f32x4 x0 = *(const f32x4*)(xr + kc * 32);
                f32x4 x1 = *(const f32x4*)(xr + kc * 32 + 4);
                bf16x8 af;
                af[0] = (__bf16)x0[0]; af[1] = (__bf16)x0[1];
                af[2] = (__bf16)x0[2]; af[3] = (__bf16)x0[3];
                af[4] = (__bf16)x1[0]; af[5] = (__bf16)x1[1];
                af[6] = (__bf16)x1[2]; af[7] = (__bf16)x1[3];
                a[mi][kc] = af;
            }
        }

        f32x4 acc[2][8] = {};
#pragma unroll
        for (int kc = 0; kc < 4; ++kc) {
#pragma unroll
            for (int nt = 0; nt < 8; ++nt) {
                bf16x8 bf = *(const bf16x8*)(&Wt[(nt * 16 + l16) * 136 + kc * 32 + lhi * 8]);
                acc[0][nt] = __builtin_amdgcn_mfma_f32_16x16x32_bf16(a[0][kc], bf, acc[0][nt], 0, 0, 0);
                acc[1][nt] = __builtin_amdgcn_mfma_f32_16x16x32_bf16(a[1][kc], bf, acc[1][nt], 0, 0, 0);
            }
        }

#pragma unroll
        for (int mi = 0; mi < 2; ++mi) {
#pragma unroll
            for (int nt = 0; nt < 8; ++nt) {
#pragma unroll
                for (int r = 0; r < 4; ++r) {
                    int orow = m0 + mi * 16 + lhi * 4 + r;
                    Y[(size_t)orow * 128 + nt * 16 + l16] = acc[mi][nt][r] + bv[nt];
                }
            }
        }
    }
}

// ---------------------------------------------------------------------------
// Edge kernel: etmp holds Ce on input; in-place becomes e_new = Ce+Dh[src]+Eh[dst].
// sigma = sigmoid(e_new); atomically aggregate num += sigma*Bh[src],
// den += sigma onto dst nodes; accumulate BN partial sums for e.
// 128 threads = one feature column each; each block walks `epb` edges.
// ---------------------------------------------------------------------------
__global__ __launch_bounds__(128) void edge_kernel(float* __restrict__ etmp,
                                                   const float* __restrict__ Dh,
                                                   const float* __restrict__ Eh,
                                                   const float* __restrict__ Bh,
                                                   const int* __restrict__ src,
                                                   const int* __restrict__ dst,
                                                   float* __restrict__ num,
                                                   float* __restrict__ den,
                                                   float* __restrict__ stats,
                                                   int E, int epb)
{
    const int d  = threadIdx.x;
    const int e0 = blockIdx.x * epb;
    const int e1 = (e0 + epb < E) ? (e0 + epb) : E;

    float s1 = 0.f, s2 = 0.f;
    for (int e = e0; e < e1; ++e) {
        const int s = src[e];
        const int td = dst[e];
        const size_t off = (size_t)e * 128 + d;
        float v = etmp[off] + Dh[(size_t)s * 128 + d] + Eh[(size_t)td * 128 + d];
        etmp[off] = v;
        float sg = 1.f / (1.f + __expf(-v));
        atomicAdd(&num[(size_t)td * 128 + d], sg * Bh[(size_t)s * 128 + d]);
        atomicAdd(&den[(size_t)td * 128 + d], sg);
        s1 += v;
        s2 += v * v;
    }
    atomicAdd(&stats[d], s1);
    atomicAdd(&stats[128 + d], s2);
}

// ---------------------------------------------------------------------------
// Node update: h_pre = Ah + num/(den+eps), in place over Ah; BN partials for h.
// ---------------------------------------------------------------------------
__global__ __launch_bounds__(128) void node_update(float* __restrict__ Ah,
                                                   const float* __restrict__ num,
                                                   const float* __restrict__ den,
                                                   float* __restrict__ stats,
                                                   int N, int npb)
{
    const int d  = threadIdx.x;
    const int i0 = blockIdx.x * npb;
    const int i1 = (i0 + npb < N) ? (i0 + npb) : N;

    float s1 = 0.f, s2 = 0.f;
    for (int i = i0; i < i1; ++i) {
        const size_t off = (size_t)i * 128 + d;
        float v = Ah[off] + num[off] / (den[off] + 1e-6f);
        Ah[off] = v;
        s1 += v;
        s2 += v * v;
    }
    atomicAdd(&stats[256 + d], s1);
    atomicAdd(&stats[384 + d], s2);
}

// ---------------------------------------------------------------------------
// BN(training, biased var) + ReLU + residual: out += relu((x-mu)*rstd*g + b)
// stats: sum at [d], sumsq at [128+d].
// ---------------------------------------------------------------------------
__global__ __launch_bounds__(128) void norm_residual(const float* __restrict__ xpre,
                                                     const float* __restrict__ stats,
                                                     const float* __restrict__ gamma,
                                                     const float* __restrict__ beta,
                                                     float* __restrict__ out,
                                                     int R, float invR)
{
    const int d = threadIdx.x;
    const float mean = stats[d] * invR;
    const float var  = stats[128 + d] * invR - mean * mean;
    const float rstd = rsqrtf(var + 1e-5f);
    const float g    = gamma[d] * rstd;
    const float bt   = beta[d];

    for (int i = blockIdx.x; i < R; i += gridDim.x) {
        const size_t off = (size_t)i * 128 + d;
        float v = (xpre[off] - mean) * g + bt;
        out[off] += fmaxf(v, 0.f);
    }
}

// ---------------------------------------------------------------------------
extern "C" void kernel_launch(void* const* d_in, const int* in_sizes, int n_in,
                              void* d_out, int out_size, void* d_ws, size_t ws_size,
                              hipStream_t stream)
{
    const float* h_in = (const float*)d_in[0];
    const float* e_in = (const float*)d_in[1];
    const float* W    = (const float*)d_in[2];
    const float* b    = (const float*)d_in[3];
    const float* gam  = (const float*)d_in[4];
    const float* bet  = (const float*)d_in[5];
    const int*   src  = (const int*)d_in[6];
    const int*   dst  = (const int*)d_in[7];

    const int N = GCN_N, E = GCN_E, D = GCN_D;
    const size_t NF = (size_t)N * D;   // 5,120,000
    const size_t EF = (size_t)E * D;   // 81,920,000

    float* out   = (float*)d_out;
    float* out_h = out;            // h_before output = input h
    float* out_e = out + NF;       // e_cur lives here; final e lands here

    float* ws    = (float*)d_ws;
    float* h_cur = ws;
    float* Ah    = h_cur + NF;
    float* Bh    = Ah + NF;
    float* Dh    = Bh + NF;
    float* Eh    = Dh + NF;
    float* num   = Eh + NF;
    float* den   = num + NF;
    float* stats = den + NF;       // 512 floats
    float* etmp  = stats + 512;    // EF floats

    hipMemcpyAsync(out_h, h_in, NF * sizeof(float), hipMemcpyDeviceToDevice, stream);
    hipMemcpyAsync(h_cur, h_in, NF * sizeof(float), hipMemcpyDeviceToDevice, stream);
    hipMemcpyAsync(out_e, e_in, EF * sizeof(float), hipMemcpyDeviceToDevice, stream);

    for (int l = 0; l < 4; ++l) {
        const float* Wl = W + (size_t)l * 5 * D * D;
        const float* bl = b + (size_t)l * 5 * D;

        // zero num, den, stats (contiguous)
        hipMemsetAsync(num, 0, (2 * NF + 512) * sizeof(float), stream);

        // node GEMMs: A, B, D, E   (M = 40000 -> 1250 iters, 313 blocks)
        gemm128<<<313, 256, 0, stream>>>(h_cur, Wl + 0 * D * D, bl + 0 * D, Ah, N);
        gemm128<<<313, 256, 0, stream>>>(h_cur, Wl + 1 * D * D, bl + 1 * D, Bh, N);
        gemm128<<<313, 256, 0, stream>>>(h_cur, Wl + 3 * D * D, bl + 3 * D, Dh, N);
        gemm128<<<313, 256, 0, stream>>>(h_cur, Wl + 4 * D * D, bl + 4 * D, Eh, N);
        // edge GEMM: Ce -> etmp   (M = 640000)
        gemm128<<<2048, 256, 0, stream>>>(out_e, Wl + 2 * D * D, bl + 2 * D, etmp, E);

        // edge update + gated aggregation + e-BN partials
        edge_kernel<<<E / 128, 128, 0, stream>>>(etmp, Dh, Eh, Bh, src, dst,
                                                 num, den, stats, E, 128);

        // node pre-activation + h-BN partials (in place over Ah)
        node_update<<<(N + 127) / 128, 128, 0, stream>>>(Ah, num, den, stats, N, 128);

        // h = h + relu(bn(h_pre));  e = e + relu(bn(e_new))
        norm_residual<<<512, 128, 0, stream>>>(Ah, stats + 256,
                                               gam + (size_t)(l * 2 + 0) * D,
                                               bet + (size_t)(l * 2 + 0) * D,
                                               h_cur, N, 1.f / (float)N);
        norm_residual<<<2048, 128, 0, stream>>>(etmp, stats,
                                                gam + (size_t)(l * 2 + 1) * D,
                                                bet + (size_t)(l * 2 + 1) * D,
                                                out_e, E, 1.f / (float)E);
    }
}